// Round 15
// baseline (338.031 us; speedup 1.0000x reference)
//
#include <hip/hip_runtime.h>
#include <math.h>

#define VEC   300
#define HID   256
#define ATT   500
#define NB    64
#define NS    128
#define G3    768     // 3*HID
#define GIC   1536    // both directions packed
#define H2    512     // 2*HID

typedef _Float16 half1;
typedef _Float16 h2_t  __attribute__((ext_vector_type(2)));
typedef _Float16 f16x8 __attribute__((ext_vector_type(8)));
typedef float    f32x4 __attribute__((ext_vector_type(4)));

struct __align__(16) H8 { h2_t a, b, c, d; };

#if __has_builtin(__builtin_amdgcn_exp2f)
#define EXP2F(x) __builtin_amdgcn_exp2f(x)
#else
#define EXP2F(x) exp2f(x)
#endif
#if __has_builtin(__builtin_amdgcn_rcpf)
#define RCPF(x) __builtin_amdgcn_rcpf(x)
#else
#define RCPF(x) (1.0f/(x))
#endif

__device__ __forceinline__ float sigm(float x){ return RCPF(1.f + EXP2F(-1.44269504f*x)); }
__device__ __forceinline__ float tanh_fast(float x){ return 1.f - 2.f*RCPF(1.f + EXP2F(2.88539008f*x)); }

#if __has_builtin(__builtin_amdgcn_fdot2)
#define FDOT(w,h,acc) __builtin_amdgcn_fdot2((w),(h),(acc),false)
#else
#define FDOT(w,h,acc) ((acc) + (float)(w).x*(float)(h).x + (float)(w).y*(float)(h).y)
#endif

// ---- prep2: pack Whh for the intra-wave-split scan.
// Thread t (0..511): u = (t>>6)*32 + (t&31), ks = (t>>5)&1.
// Slot (dir*192 + p*3 + j)*512 + t = rows k0=ks*128+2p, +2p+1, column u, gate j.
__global__ __launch_bounds__(256) void k_prep2(const float* __restrict__ Wf,
                       const float* __restrict__ Wb, h2_t* __restrict__ Wpk){
  int o = blockIdx.x*256 + threadIdx.x;    // < 196608
  int t = o & 511;
  int rest = o >> 9;                       // dir*192 + p*3 + j
  int j = rest % 3;
  int p = (rest/3) & 63;
  int dir = rest / 192;
  int u = (t >> 6)*32 + (t & 31);
  int ks = (t >> 5) & 1;
  const float* W = dir ? Wb : Wf;
  int k0 = ks*128 + 2*p;
  h2_t w;
  w.x = (half1)W[(j*HID+u)*HID + k0];
  w.y = (half1)W[(j*HID+u)*HID + k0 + 1];
  Wpk[o] = w;
}

// ---- prepA: afW fp32 -> fp16, zero-padded to 512 rows.
__global__ __launch_bounds__(256) void k_prepA(const float* __restrict__ afW,
                       half1* __restrict__ afW16){
  int o = blockIdx.x*256 + threadIdx.x;    // < 262144
  int n = o >> 9, k = o & 511;
  afW16[o] = (half1)((n < ATT) ? afW[n*H2 + k] : 0.f);
}

// ---- input projection: fp16 MFMA GEMM with fused embedding gather (unchanged).
__global__ __launch_bounds__(256)
__attribute__((amdgpu_waves_per_eu(4, 4)))
void k_gi_mfma(const int* __restrict__ x,
      const float* __restrict__ emb,
      const float* __restrict__ Wf, const float* __restrict__ Wb,
      const float* __restrict__ bf, const float* __restrict__ bb,
      float* __restrict__ gi){
  __shared__ half1 Al[128*40];
  __shared__ half1 Bl[128*40];
  __shared__ int   xi[128];
  const int t = threadIdx.x;
  const int row0 = blockIdx.x * 128;
  const int col0 = blockIdx.y * 128;
  if (t < 128) {
    int i = row0 + t; int s = i >> 6; int b = i & 63;
    xi[t] = x[b*NS + s];
  }
  __syncthreads();

  const int lane = t & 63, wid = t >> 6;
  const int wr = wid >> 1, wc = wid & 1;
  const int l15 = lane & 15, lk = lane >> 4;

  f32x4 acc[4][4];
#pragma unroll
  for (int i = 0; i < 4; ++i)
#pragma unroll
    for (int j = 0; j < 4; ++j) acc[i][j] = (f32x4){0.f,0.f,0.f,0.f};

  for (int ks = 0; ks < 10; ++ks) {
#pragma unroll
    for (int l = 0; l < 8; ++l) {
      int idx = l*256 + t;
      int row = idx >> 4;
      int kp  = idx & 15;
      int kk  = ks*32 + kp*2;
      h2_t va; va.x = (half1)0.f; va.y = (half1)0.f;
      h2_t vb; vb.x = (half1)0.f; vb.y = (half1)0.f;
      if (kk < VEC) {
        float2 e = *reinterpret_cast<const float2*>(&emb[(long)xi[row]*VEC + kk]);
        va.x = (half1)e.x; va.y = (half1)e.y;
        int g = col0 + row;
        const float* W = (g < G3) ? &Wf[(long)g*VEC] : &Wb[(long)(g-G3)*VEC];
        float2 w2 = *reinterpret_cast<const float2*>(&W[kk]);
        vb.x = (half1)w2.x; vb.y = (half1)w2.y;
      }
      *reinterpret_cast<h2_t*>(&Al[row*40 + kp*2]) = va;
      *reinterpret_cast<h2_t*>(&Bl[row*40 + kp*2]) = vb;
    }
    __syncthreads();
    f16x8 af[4], bfq[4];
#pragma unroll
    for (int i = 0; i < 4; ++i)
      af[i]  = *reinterpret_cast<const f16x8*>(&Al[(wr*64 + i*16 + l15)*40 + lk*8]);
#pragma unroll
    for (int j = 0; j < 4; ++j)
      bfq[j] = *reinterpret_cast<const f16x8*>(&Bl[(wc*64 + j*16 + l15)*40 + lk*8]);
#pragma unroll
    for (int i = 0; i < 4; ++i)
#pragma unroll
      for (int j = 0; j < 4; ++j)
        acc[i][j] = __builtin_amdgcn_mfma_f32_16x16x32_f16(af[i], bfq[j], acc[i][j], 0, 0, 0);
    __syncthreads();
  }

#pragma unroll
  for (int j = 0; j < 4; ++j) {
    int gcol = col0 + wc*64 + j*16 + l15;
    float bj = (gcol < G3) ? bf[gcol] : bb[gcol - G3];
#pragma unroll
    for (int i = 0; i < 4; ++i) {
      int grow0 = row0 + wr*64 + i*16 + lk*4;
#pragma unroll
      for (int q = 0; q < 4; ++q)
        gi[(long)(grow0 + q)*GIC + gcol] = acc[i][j][q] + bj;
    }
  }
}

// ======== GRU scan v6: intra-wave 2-way k-split, ONE barrier/step, no part LDS.
// 512 thr = 8 waves; wave w owns u in [w*32, w*32+32); lane = ul | ks<<5.
// All weights in 192 named h2 regs/thread (proven no-spill). h history in LDS.
#define DECL12(X,g,UNUSED) h2_t X##g##a0,X##g##a1,X##g##a2, X##g##b0,X##g##b1,X##g##b2, \
                                X##g##c0,X##g##c1,X##g##c2, X##g##d0,X##g##d1,X##g##d2;
#define LOAD12(X,g,PB) \
  X##g##a0=wp[(((PB)+4*(g)+0)*3+0)*512]; X##g##a1=wp[(((PB)+4*(g)+0)*3+1)*512]; X##g##a2=wp[(((PB)+4*(g)+0)*3+2)*512]; \
  X##g##b0=wp[(((PB)+4*(g)+1)*3+0)*512]; X##g##b1=wp[(((PB)+4*(g)+1)*3+1)*512]; X##g##b2=wp[(((PB)+4*(g)+1)*3+2)*512]; \
  X##g##c0=wp[(((PB)+4*(g)+2)*3+0)*512]; X##g##c1=wp[(((PB)+4*(g)+2)*3+1)*512]; X##g##c2=wp[(((PB)+4*(g)+2)*3+2)*512]; \
  X##g##d0=wp[(((PB)+4*(g)+3)*3+0)*512]; X##g##d1=wp[(((PB)+4*(g)+3)*3+1)*512]; X##g##d2=wp[(((PB)+4*(g)+3)*3+2)*512];
#define FMA12(X,g,BOFF) { \
  H8 hv = *reinterpret_cast<const H8*>(&hr[(BOFF) + (g)*8]); \
  a0=FDOT(X##g##a0,hv.a,a0); a1=FDOT(X##g##a1,hv.a,a1); a2=FDOT(X##g##a2,hv.a,a2); \
  a0=FDOT(X##g##b0,hv.b,a0); a1=FDOT(X##g##b1,hv.b,a1); a2=FDOT(X##g##b2,hv.b,a2); \
  a0=FDOT(X##g##c0,hv.c,a0); a1=FDOT(X##g##c1,hv.c,a1); a2=FDOT(X##g##c2,hv.c,a2); \
  a0=FDOT(X##g##d0,hv.d,a0); a1=FDOT(X##g##d1,hv.d,a1); a2=FDOT(X##g##d2,hv.d,a2); }
#define GRP8(M,X,A2) M(X,0,A2) M(X,1,A2) M(X,2,A2) M(X,3,A2) M(X,4,A2) M(X,5,A2) M(X,6,A2) M(X,7,A2)

__global__ __launch_bounds__(512)
__attribute__((amdgpu_waves_per_eu(2, 2)))
void k_scan_reg6(const float* __restrict__ gi,
     const h2_t* __restrict__ Wpk,
     const float* __restrict__ bhf, const float* __restrict__ bhb,
     float* __restrict__ hseq){
  __shared__ __align__(16) half1 hist[129*256];  // row tt = h before step tt; 66KB
  const int t    = threadIdx.x;
  const int lane = t & 63;
  const int ul   = lane & 31;
  const int ks   = lane >> 5;          // 0 or 1
  const int w    = t >> 6;
  const int u    = w*32 + ul;
  const int ks128 = ks * 128;
  const int dir  = blockIdx.x & 1;
  const int b    = blockIdx.x >> 1;
  const float* bhh = dir ? bhb : bhf;
  const h2_t* wp = Wpk + (long)dir*98304 + t;

  GRP8(DECL12, A, 0)
  GRP8(DECL12, B, 0)
  GRP8(LOAD12, A, 0)     // pairs 0..31  -> slice rows 0..63
  GRP8(LOAD12, B, 32)    // pairs 32..63 -> slice rows 64..127

  const bool fin = (ks == 0);
  float bh0=0.f, bh1=0.f, bh2=0.f;
  if (fin) { bh0 = bhh[u]; bh1 = bhh[HID+u]; bh2 = bhh[2*HID+u]; }
  if (t < 256) hist[t] = (half1)0.f;   // h0 = 0
  float hprev = 0.f;

  const long gstep = dir ? -(long)NB*GIC : (long)NB*GIC;
  long gbase = ((long)(dir ? (NS-1) : 0)*NB + b)*GIC + dir*G3 + u;
  __syncthreads();

#pragma unroll 1
  for (int tt = 0; tt < NS; ++tt) {
    float i0=0.f, i1=0.f, i2=0.f;
    if (fin) {                         // issued before dot phase; used after reduce
      i0 = gi[gbase]; i1 = gi[gbase+HID]; i2 = gi[gbase+2*HID];
    }
    const half1* hr = &hist[tt*256 + ks128];
    float a0=0.f, a1=0.f, a2=0.f;
    GRP8(FMA12, A, 0)                  // slice rows 0..63
    GRP8(FMA12, B, 64)                 // slice rows 64..127
    a0 += __shfl_xor(a0, 32, 64);
    a1 += __shfl_xor(a1, 32, 64);
    a2 += __shfl_xor(a2, 32, 64);
    if (fin) {
      float g0 = bh0 + a0;
      float g1 = bh1 + a1;
      float g2 = bh2 + a2;
      float r  = sigm(i0 + g0);
      float zg = sigm(i1 + g1);
      float n  = tanh_fast(i2 + r*g2);
      float hn = (1.f - zg)*n + zg*hprev;
      hprev = hn;
      hist[(tt+1)*256 + u] = (half1)hn;
    }
    gbase += gstep;
    __syncthreads();                   // write of row tt+1 visible to all
  }

  // bulk dump: hist rows 1..128 -> hseq (coalesced float4)
#pragma unroll 1
  for (int it = 0; it < 16; ++it) {
    int idx = it*512 + t;              // 0..8191
    int ttr = idx >> 6;                // 0..127
    int c4  = (idx & 63) * 4;          // 0,4,..,252
    int s   = dir ? (NS-1-ttr) : ttr;
    h2_t p0 = *reinterpret_cast<const h2_t*>(&hist[(ttr+1)*256 + c4]);
    h2_t p1 = *reinterpret_cast<const h2_t*>(&hist[(ttr+1)*256 + c4 + 2]);
    float4 v; v.x = (float)p0.x; v.y = (float)p0.y; v.z = (float)p1.x; v.w = (float)p1.y;
    *reinterpret_cast<float4*>(&hseq[((long)b*NS + s)*H2 + dir*HID + c4]) = v;
  }
}

// ---- fused attention: scores (MFMA) + softmax + pool + fc, one block per batch.
__global__ __launch_bounds__(512)
void k_att12(const float* __restrict__ hseq, const half1* __restrict__ afW16,
    const float* __restrict__ afb, const float* __restrict__ attw,
    const int* __restrict__ z, const float* __restrict__ fcW,
    const float* __restrict__ fcb, float* __restrict__ out){
  __shared__ half1 ht[128*520];        // 133KB
  __shared__ float usl[NS];
  __shared__ float att[NS];
  __shared__ float red[512];
  const int t  = threadIdx.x;
  const int b  = blockIdx.x;
  const int lane = t & 63, w = t >> 6;  // 8 waves
  const int l15 = lane & 15, lk = lane >> 4;

#pragma unroll 4
  for (int l = 0; l < 128; ++l) {      // stage 128x512 fp32 -> fp16
    int idx = l*512 + t;
    int sl = idx >> 9, c = idx & 511;
    ht[sl*520 + c] = (half1)hseq[((long)b*NS + sl)*H2 + c];
  }
  __syncthreads();

  // wave w computes scores for s-rows [w*16, w*16+16)
  const int zb = z[b];
  float us[4];
#pragma unroll
  for (int q = 0; q < 4; ++q) us[q] = 0.f;

#pragma unroll 1
  for (int nc = 0; nc < 8; ++nc) {     // n-chunks of 64
    f32x4 acc[4];
#pragma unroll
    for (int nf = 0; nf < 4; ++nf) acc[nf] = (f32x4){0.f,0.f,0.f,0.f};
#pragma unroll 2
    for (int ksn = 0; ksn < 16; ++ksn) {
      f16x8 af = *reinterpret_cast<const f16x8*>(&ht[(w*16 + l15)*520 + ksn*32 + lk*8]);
#pragma unroll
      for (int nf = 0; nf < 4; ++nf) {
        int n = nc*64 + nf*16 + l15;
        f16x8 bf = *reinterpret_cast<const f16x8*>(&afW16[(long)n*512 + ksn*32 + lk*8]);
        acc[nf] = __builtin_amdgcn_mfma_f32_16x16x32_f16(af, bf, acc[nf], 0, 0, 0);
      }
    }
#pragma unroll
    for (int nf = 0; nf < 4; ++nf) {
      int n = nc*64 + nf*16 + l15;
      float ab = (n < ATT) ? afb[n] : 0.f;
      float aw = (n < ATT) ? attw[zb*ATT + n] : 0.f;
#pragma unroll
      for (int q = 0; q < 4; ++q)
        us[q] += tanh_fast(acc[nf][q] + ab) * aw;
    }
  }
  // reduce over l15 (16 lanes hold partials over n for the same s-row)
#pragma unroll
  for (int off = 1; off < 16; off <<= 1)
#pragma unroll
    for (int q = 0; q < 4; ++q) us[q] += __shfl_xor(us[q], off, 64);
  if (l15 == 0) {
#pragma unroll
    for (int q = 0; q < 4; ++q)
      usl[w*16 + lk*4 + q] = us[q];
  }
  __syncthreads();

  // softmax over 128
  float v = (t < NS) ? usl[t] : -3.4e38f;
  red[t] = v; __syncthreads();
  for (int off = 256; off >= 1; off >>= 1) {
    if (t < off && t + off < 512) red[t] = fmaxf(red[t], red[t+off]);
    __syncthreads();
  }
  float mx = red[0]; __syncthreads();
  float e = (t < NS) ? EXP2F(1.44269504f*(v - mx)) : 0.f;
  red[t] = e; __syncthreads();
  for (int off = 256; off >= 1; off >>= 1) {
    if (t < off && t + off < 512) red[t] += red[t+off];
    __syncthreads();
  }
  float sm = red[0]; __syncthreads();
  if (t < NS) att[t] = e / sm;
  __syncthreads();

  // pool: c = t (512 cols), then fc
  float p = 0.f;
#pragma unroll 4
  for (int s = 0; s < NS; ++s)
    p += att[s] * (float)ht[s*520 + t];

  for (int j = 0; j < 2; ++j) {
    red[t] = p * fcW[j*H2 + t]; __syncthreads();
    for (int off = 256; off >= 1; off >>= 1) {
      if (t < off) red[t] += red[t+off];
      __syncthreads();
    }
    if (t == 0) out[b*2+j] = red[0] + fcb[j];
    __syncthreads();
  }
}

extern "C" void kernel_launch(void* const* d_in, const int* in_sizes, int n_in,
                              void* d_out, int out_size, void* d_ws, size_t ws_size,
                              hipStream_t stream) {
  const int*   x     = (const int*)  d_in[0];
  const int*   z     = (const int*)  d_in[1];
  const float* emb   = (const float*)d_in[2];
  const float* Wih_f = (const float*)d_in[3];
  const float* Whh_f = (const float*)d_in[4];
  const float* bih_f = (const float*)d_in[5];
  const float* bhh_f = (const float*)d_in[6];
  const float* Wih_b = (const float*)d_in[7];
  const float* Whh_b = (const float*)d_in[8];
  const float* bih_b = (const float*)d_in[9];
  const float* bhh_b = (const float*)d_in[10];
  const float* afW   = (const float*)d_in[11];
  const float* afb   = (const float*)d_in[12];
  const float* attw  = (const float*)d_in[13];
  const float* fcW   = (const float*)d_in[14];
  const float* fcb   = (const float*)d_in[15];

  float* ws    = (float*)d_ws;
  h2_t*  Wpk   = (h2_t*)ws;                        // 196608 * 4B
  half1* afW16 = (half1*)(ws + 196608);            // 512*512 halves
  float* giW   = ws   + 196608 + 131072;           // 8192*1536
  float* hseq  = giW  + 12582912;                  // 64*128*512

  k_prep2<<<dim3(768),  dim3(256), 0, stream>>>(Whh_f, Whh_b, Wpk);
  k_prepA<<<dim3(1024), dim3(256), 0, stream>>>(afW, afW16);
  k_gi_mfma<<<dim3(64,12), dim3(256), 0, stream>>>(x, emb, Wih_f, Wih_b, bih_f, bih_b, giW);
  k_scan_reg6<<<dim3(128), dim3(512), 0, stream>>>(giW, Wpk, bhh_f, bhh_b, hseq);
  k_att12<<<dim3(64), dim3(512), 0, stream>>>(hseq, afW16, afb, attw, z, fcW, fcb, (float*)d_out);
}

// Round 16
// 233.732 us; speedup vs baseline: 1.4462x; 1.4462x over previous
//
#include <hip/hip_runtime.h>
#include <math.h>

#define VEC   300
#define HID   256
#define ATT   500
#define NB    64
#define NS    128
#define G3    768     // 3*HID
#define GIC   1536    // both directions packed
#define H2    512     // 2*HID

typedef _Float16 half1;
typedef _Float16 h2_t  __attribute__((ext_vector_type(2)));
typedef _Float16 f16x8 __attribute__((ext_vector_type(8)));
typedef float    f32x4 __attribute__((ext_vector_type(4)));

struct __align__(16) H8 { h2_t a, b, c, d; };

#if __has_builtin(__builtin_amdgcn_exp2f)
#define EXP2F(x) __builtin_amdgcn_exp2f(x)
#else
#define EXP2F(x) exp2f(x)
#endif
#if __has_builtin(__builtin_amdgcn_rcpf)
#define RCPF(x) __builtin_amdgcn_rcpf(x)
#else
#define RCPF(x) (1.0f/(x))
#endif

__device__ __forceinline__ float sigm(float x){ return RCPF(1.f + EXP2F(-1.44269504f*x)); }
__device__ __forceinline__ float tanh_fast(float x){ return 1.f - 2.f*RCPF(1.f + EXP2F(2.88539008f*x)); }

#if __has_builtin(__builtin_amdgcn_fdot2)
#define FDOT(w,h,acc) __builtin_amdgcn_fdot2((w),(h),(acc),false)
#else
#define FDOT(w,h,acc) ((acc) + (float)(w).x*(float)(h).x + (float)(w).y*(float)(h).y)
#endif

// ---- prep2: pack Whh for the intra-wave-split scan.
// Thread t (0..511): u = (t>>6)*32 + (t&31), ks = (t>>5)&1.
// Slot (dir*192 + p*3 + j)*512 + t = rows k0=ks*128+2p, +2p+1, column u, gate j.
__global__ __launch_bounds__(256) void k_prep2(const float* __restrict__ Wf,
                       const float* __restrict__ Wb, h2_t* __restrict__ Wpk){
  int o = blockIdx.x*256 + threadIdx.x;    // < 196608
  int t = o & 511;
  int rest = o >> 9;                       // dir*192 + p*3 + j
  int j = rest % 3;
  int p = (rest/3) & 63;
  int dir = rest / 192;
  int u = (t >> 6)*32 + (t & 31);
  int ks = (t >> 5) & 1;
  const float* W = dir ? Wb : Wf;
  int k0 = ks*128 + 2*p;
  h2_t w;
  w.x = (half1)W[(j*HID+u)*HID + k0];
  w.y = (half1)W[(j*HID+u)*HID + k0 + 1];
  Wpk[o] = w;
}

// ---- prepA: afW fp32 -> fp16, zero-padded to 512 rows.
__global__ __launch_bounds__(256) void k_prepA(const float* __restrict__ afW,
                       half1* __restrict__ afW16){
  int o = blockIdx.x*256 + threadIdx.x;    // < 262144
  int n = o >> 9, k = o & 511;
  afW16[o] = (half1)((n < ATT) ? afW[n*H2 + k] : 0.f);
}

// ---- input projection: fp16 MFMA GEMM with fused embedding gather (unchanged).
__global__ __launch_bounds__(256)
__attribute__((amdgpu_waves_per_eu(4, 4)))
void k_gi_mfma(const int* __restrict__ x,
      const float* __restrict__ emb,
      const float* __restrict__ Wf, const float* __restrict__ Wb,
      const float* __restrict__ bf, const float* __restrict__ bb,
      float* __restrict__ gi){
  __shared__ half1 Al[128*40];
  __shared__ half1 Bl[128*40];
  __shared__ int   xi[128];
  const int t = threadIdx.x;
  const int row0 = blockIdx.x * 128;
  const int col0 = blockIdx.y * 128;
  if (t < 128) {
    int i = row0 + t; int s = i >> 6; int b = i & 63;
    xi[t] = x[b*NS + s];
  }
  __syncthreads();

  const int lane = t & 63, wid = t >> 6;
  const int wr = wid >> 1, wc = wid & 1;
  const int l15 = lane & 15, lk = lane >> 4;

  f32x4 acc[4][4];
#pragma unroll
  for (int i = 0; i < 4; ++i)
#pragma unroll
    for (int j = 0; j < 4; ++j) acc[i][j] = (f32x4){0.f,0.f,0.f,0.f};

  for (int ks = 0; ks < 10; ++ks) {
#pragma unroll
    for (int l = 0; l < 8; ++l) {
      int idx = l*256 + t;
      int row = idx >> 4;
      int kp  = idx & 15;
      int kk  = ks*32 + kp*2;
      h2_t va; va.x = (half1)0.f; va.y = (half1)0.f;
      h2_t vb; vb.x = (half1)0.f; vb.y = (half1)0.f;
      if (kk < VEC) {
        float2 e = *reinterpret_cast<const float2*>(&emb[(long)xi[row]*VEC + kk]);
        va.x = (half1)e.x; va.y = (half1)e.y;
        int g = col0 + row;
        const float* W = (g < G3) ? &Wf[(long)g*VEC] : &Wb[(long)(g-G3)*VEC];
        float2 w2 = *reinterpret_cast<const float2*>(&W[kk]);
        vb.x = (half1)w2.x; vb.y = (half1)w2.y;
      }
      *reinterpret_cast<h2_t*>(&Al[row*40 + kp*2]) = va;
      *reinterpret_cast<h2_t*>(&Bl[row*40 + kp*2]) = vb;
    }
    __syncthreads();
    f16x8 af[4], bfq[4];
#pragma unroll
    for (int i = 0; i < 4; ++i)
      af[i]  = *reinterpret_cast<const f16x8*>(&Al[(wr*64 + i*16 + l15)*40 + lk*8]);
#pragma unroll
    for (int j = 0; j < 4; ++j)
      bfq[j] = *reinterpret_cast<const f16x8*>(&Bl[(wc*64 + j*16 + l15)*40 + lk*8]);
#pragma unroll
    for (int i = 0; i < 4; ++i)
#pragma unroll
      for (int j = 0; j < 4; ++j)
        acc[i][j] = __builtin_amdgcn_mfma_f32_16x16x32_f16(af[i], bfq[j], acc[i][j], 0, 0, 0);
    __syncthreads();
  }

#pragma unroll
  for (int j = 0; j < 4; ++j) {
    int gcol = col0 + wc*64 + j*16 + l15;
    float bj = (gcol < G3) ? bf[gcol] : bb[gcol - G3];
#pragma unroll
    for (int i = 0; i < 4; ++i) {
      int grow0 = row0 + wr*64 + i*16 + lk*4;
#pragma unroll
      for (int q = 0; q < 4; ++q)
        gi[(long)(grow0 + q)*GIC + gcol] = acc[i][j][q] + bj;
    }
  }
}

// ======== GRU scan v6: intra-wave 2-way k-split, ONE barrier/step, no part LDS.
// 512 thr = 8 waves; wave w owns u in [w*32, w*32+32); lane = ul | ks<<5.
// All weights in 192 named h2 regs/thread. h history in LDS, bulk dump at end.
#define DECL12(X,g,UNUSED) h2_t X##g##a0,X##g##a1,X##g##a2, X##g##b0,X##g##b1,X##g##b2, \
                                X##g##c0,X##g##c1,X##g##c2, X##g##d0,X##g##d1,X##g##d2;
#define LOAD12(X,g,PB) \
  X##g##a0=wp[(((PB)+4*(g)+0)*3+0)*512]; X##g##a1=wp[(((PB)+4*(g)+0)*3+1)*512]; X##g##a2=wp[(((PB)+4*(g)+0)*3+2)*512]; \
  X##g##b0=wp[(((PB)+4*(g)+1)*3+0)*512]; X##g##b1=wp[(((PB)+4*(g)+1)*3+1)*512]; X##g##b2=wp[(((PB)+4*(g)+1)*3+2)*512]; \
  X##g##c0=wp[(((PB)+4*(g)+2)*3+0)*512]; X##g##c1=wp[(((PB)+4*(g)+2)*3+1)*512]; X##g##c2=wp[(((PB)+4*(g)+2)*3+2)*512]; \
  X##g##d0=wp[(((PB)+4*(g)+3)*3+0)*512]; X##g##d1=wp[(((PB)+4*(g)+3)*3+1)*512]; X##g##d2=wp[(((PB)+4*(g)+3)*3+2)*512];
#define FMA12(X,g,BOFF) { \
  H8 hv = *reinterpret_cast<const H8*>(&hr[(BOFF) + (g)*8]); \
  a0=FDOT(X##g##a0,hv.a,a0); a1=FDOT(X##g##a1,hv.a,a1); a2=FDOT(X##g##a2,hv.a,a2); \
  a0=FDOT(X##g##b0,hv.b,a0); a1=FDOT(X##g##b1,hv.b,a1); a2=FDOT(X##g##b2,hv.b,a2); \
  a0=FDOT(X##g##c0,hv.c,a0); a1=FDOT(X##g##c1,hv.c,a1); a2=FDOT(X##g##c2,hv.c,a2); \
  a0=FDOT(X##g##d0,hv.d,a0); a1=FDOT(X##g##d1,hv.d,a1); a2=FDOT(X##g##d2,hv.d,a2); }
#define GRP8(M,X,A2) M(X,0,A2) M(X,1,A2) M(X,2,A2) M(X,3,A2) M(X,4,A2) M(X,5,A2) M(X,6,A2) M(X,7,A2)

__global__ __launch_bounds__(512)
__attribute__((amdgpu_waves_per_eu(2, 2)))
void k_scan_reg6(const float* __restrict__ gi,
     const h2_t* __restrict__ Wpk,
     const float* __restrict__ bhf, const float* __restrict__ bhb,
     float* __restrict__ hseq){
  __shared__ __align__(16) half1 hist[129*256];  // row tt = h before step tt; 66KB
  const int t    = threadIdx.x;
  const int lane = t & 63;
  const int ul   = lane & 31;
  const int ks   = lane >> 5;          // 0 or 1
  const int w    = t >> 6;
  const int u    = w*32 + ul;
  const int ks128 = ks * 128;
  const int dir  = blockIdx.x & 1;
  const int b    = blockIdx.x >> 1;
  const float* bhh = dir ? bhb : bhf;
  const h2_t* wp = Wpk + (long)dir*98304 + t;

  GRP8(DECL12, A, 0)
  GRP8(DECL12, B, 0)
  GRP8(LOAD12, A, 0)     // pairs 0..31  -> slice rows 0..63
  GRP8(LOAD12, B, 32)    // pairs 32..63 -> slice rows 64..127

  const bool fin = (ks == 0);
  float bh0=0.f, bh1=0.f, bh2=0.f;
  if (fin) { bh0 = bhh[u]; bh1 = bhh[HID+u]; bh2 = bhh[2*HID+u]; }
  if (t < 256) hist[t] = (half1)0.f;   // h0 = 0
  float hprev = 0.f;

  const long gstep = dir ? -(long)NB*GIC : (long)NB*GIC;
  long gbase = ((long)(dir ? (NS-1) : 0)*NB + b)*GIC + dir*G3 + u;
  __syncthreads();

#pragma unroll 1
  for (int tt = 0; tt < NS; ++tt) {
    float i0=0.f, i1=0.f, i2=0.f;
    if (fin) {                         // issued before dot phase; used after reduce
      i0 = gi[gbase]; i1 = gi[gbase+HID]; i2 = gi[gbase+2*HID];
    }
    const half1* hr = &hist[tt*256 + ks128];
    float a0=0.f, a1=0.f, a2=0.f;
    GRP8(FMA12, A, 0)                  // slice rows 0..63
    GRP8(FMA12, B, 64)                 // slice rows 64..127
    a0 += __shfl_xor(a0, 32, 64);
    a1 += __shfl_xor(a1, 32, 64);
    a2 += __shfl_xor(a2, 32, 64);
    if (fin) {
      float g0 = bh0 + a0;
      float g1 = bh1 + a1;
      float g2 = bh2 + a2;
      float r  = sigm(i0 + g0);
      float zg = sigm(i1 + g1);
      float n  = tanh_fast(i2 + r*g2);
      float hn = (1.f - zg)*n + zg*hprev;
      hprev = hn;
      hist[(tt+1)*256 + u] = (half1)hn;
    }
    gbase += gstep;
    __syncthreads();                   // write of row tt+1 visible to all
  }

  // bulk dump: hist rows 1..128 -> hseq (coalesced float4)
#pragma unroll 1
  for (int it = 0; it < 16; ++it) {
    int idx = it*512 + t;              // 0..8191
    int ttr = idx >> 6;                // 0..127
    int c4  = (idx & 63) * 4;          // 0,4,..,252
    int s   = dir ? (NS-1-ttr) : ttr;
    h2_t p0 = *reinterpret_cast<const h2_t*>(&hist[(ttr+1)*256 + c4]);
    h2_t p1 = *reinterpret_cast<const h2_t*>(&hist[(ttr+1)*256 + c4 + 2]);
    float4 v; v.x = (float)p0.x; v.y = (float)p0.y; v.z = (float)p1.x; v.w = (float)p1.y;
    *reinterpret_cast<float4*>(&hseq[((long)b*NS + s)*H2 + dir*HID + c4]) = v;
  }
}

// ---- attention scores via MFMA (round-14 version restored: grid 64x4, 33KB LDS).
__global__ __launch_bounds__(256)
__attribute__((amdgpu_waves_per_eu(4, 4)))
void k_att1_mfma(const float* __restrict__ hseq, const half1* __restrict__ afW16,
    const float* __restrict__ afb, const float* __restrict__ attw,
    const int* __restrict__ z, float* __restrict__ ub){
  __shared__ half1 Ah[32*520];
  __shared__ float red[4*32];
  const int t  = threadIdx.x;
  const int b  = blockIdx.x;
  const int s0 = blockIdx.y * 32;
  const int lane = t & 63, w = t >> 6;
  const int l15 = lane & 15, lk = lane >> 4;

#pragma unroll
  for (int l = 0; l < 64; ++l) {
    int idx = l*256 + t;
    int sl = idx >> 9, c = idx & 511;
    Ah[sl*520 + c] = (half1)hseq[((long)b*NS + s0 + sl)*H2 + c];
  }
  __syncthreads();

  f32x4 acc[2][8];
#pragma unroll
  for (int i = 0; i < 2; ++i)
#pragma unroll
    for (int j = 0; j < 8; ++j) acc[i][j] = (f32x4){0.f,0.f,0.f,0.f};

#pragma unroll 2
  for (int ksn = 0; ksn < 16; ++ksn) {
    f16x8 af[2];
#pragma unroll
    for (int mt = 0; mt < 2; ++mt)
      af[mt] = *reinterpret_cast<const f16x8*>(&Ah[(mt*16 + l15)*520 + ksn*32 + lk*8]);
#pragma unroll
    for (int nt = 0; nt < 8; ++nt) {
      int n = w*128 + nt*16 + l15;
      f16x8 bf = *reinterpret_cast<const f16x8*>(&afW16[(long)n*512 + ksn*32 + lk*8]);
#pragma unroll
      for (int mt = 0; mt < 2; ++mt)
        acc[mt][nt] = __builtin_amdgcn_mfma_f32_16x16x32_f16(af[mt], bf, acc[mt][nt], 0, 0, 0);
    }
  }

  float us[8];
#pragma unroll
  for (int i = 0; i < 8; ++i) us[i] = 0.f;
  const int zb = z[b];
#pragma unroll
  for (int nt = 0; nt < 8; ++nt) {
    int n = w*128 + nt*16 + l15;
    float ab = (n < ATT) ? afb[n] : 0.f;
    float aw = (n < ATT) ? attw[zb*ATT + n] : 0.f;
#pragma unroll
    for (int mt = 0; mt < 2; ++mt)
#pragma unroll
      for (int q = 0; q < 4; ++q)
        us[mt*4+q] += tanh_fast(acc[mt][nt][q] + ab) * aw;
  }
#pragma unroll
  for (int off = 1; off < 16; off <<= 1)
#pragma unroll
    for (int i = 0; i < 8; ++i) us[i] += __shfl_xor(us[i], off, 64);
  if (l15 == 0) {
#pragma unroll
    for (int i = 0; i < 8; ++i) {
      int row = (i >> 2)*16 + lk*4 + (i & 3);
      red[w*32 + row] = us[i];
    }
  }
  __syncthreads();
  if (t < 32)
    ub[b*NS + s0 + t] = red[t] + red[32+t] + red[64+t] + red[96+t];
}

// ---- softmax + pooled + fc (round-14 version restored)
__global__ __launch_bounds__(256) void k_att2(const float* __restrict__ hseq,
   const float* __restrict__ ub, const float* __restrict__ fcW,
   const float* __restrict__ fcb, float* __restrict__ out){
  __shared__ float att[NS];
  __shared__ float red[256];
  __shared__ float pool[H2];
  const int t = threadIdx.x, b = blockIdx.x;
  float v = (t < NS) ? ub[b*NS + t] : -3.4e38f;
  red[t] = v; __syncthreads();
  for (int off = 128; off >= 1; off >>= 1) {
    if (t < off) red[t] = fmaxf(red[t], red[t+off]);
    __syncthreads();
  }
  float mx = red[0]; __syncthreads();
  float e = (t < NS) ? EXP2F(1.44269504f*(v - mx)) : 0.f;
  red[t] = e; __syncthreads();
  for (int off = 128; off >= 1; off >>= 1) {
    if (t < off) red[t] += red[t+off];
    __syncthreads();
  }
  float sm = red[0]; __syncthreads();
  if (t < NS) att[t] = e / sm;
  __syncthreads();
#pragma unroll
  for (int rep = 0; rep < 2; ++rep) {
    int c = rep*256 + t;
    float acc = 0.f;
#pragma unroll 4
    for (int s = 0; s < NS; ++s) acc += att[s] * hseq[((long)b*NS + s)*H2 + c];
    pool[c] = acc;
  }
  __syncthreads();
  for (int j = 0; j < 2; ++j) {
    float p = pool[t]*fcW[j*H2+t] + pool[t+256]*fcW[j*H2+t+256];
    red[t] = p; __syncthreads();
    for (int off = 128; off >= 1; off >>= 1) {
      if (t < off) red[t] += red[t+off];
      __syncthreads();
    }
    if (t == 0) out[b*2+j] = red[0] + fcb[j];
    __syncthreads();
  }
}

extern "C" void kernel_launch(void* const* d_in, const int* in_sizes, int n_in,
                              void* d_out, int out_size, void* d_ws, size_t ws_size,
                              hipStream_t stream) {
  const int*   x     = (const int*)  d_in[0];
  const int*   z     = (const int*)  d_in[1];
  const float* emb   = (const float*)d_in[2];
  const float* Wih_f = (const float*)d_in[3];
  const float* Whh_f = (const float*)d_in[4];
  const float* bih_f = (const float*)d_in[5];
  const float* bhh_f = (const float*)d_in[6];
  const float* Wih_b = (const float*)d_in[7];
  const float* Whh_b = (const float*)d_in[8];
  const float* bih_b = (const float*)d_in[9];
  const float* bhh_b = (const float*)d_in[10];
  const float* afW   = (const float*)d_in[11];
  const float* afb   = (const float*)d_in[12];
  const float* attw  = (const float*)d_in[13];
  const float* fcW   = (const float*)d_in[14];
  const float* fcb   = (const float*)d_in[15];

  float* ws    = (float*)d_ws;
  h2_t*  Wpk   = (h2_t*)ws;                        // 196608 * 4B
  half1* afW16 = (half1*)(ws + 196608);            // 512*512 halves
  float* giW   = ws   + 196608 + 131072;           // 8192*1536
  float* hseq  = giW  + 12582912;                  // 64*128*512
  float* ubuf  = hseq + 4194304;                   // 64*128

  k_prep2<<<dim3(768),  dim3(256), 0, stream>>>(Whh_f, Whh_b, Wpk);
  k_prepA<<<dim3(1024), dim3(256), 0, stream>>>(afW, afW16);
  k_gi_mfma<<<dim3(64,12), dim3(256), 0, stream>>>(x, emb, Wih_f, Wih_b, bih_f, bih_b, giW);
  k_scan_reg6<<<dim3(128), dim3(512), 0, stream>>>(giW, Wpk, bhh_f, bhh_b, hseq);
  k_att1_mfma<<<dim3(64,4), dim3(256), 0, stream>>>(hseq, afW16, afb, attw, z, ubuf);
  k_att2<<<dim3(64), dim3(256), 0, stream>>>(hseq, ubuf, fcW, fcb, (float*)d_out);
}